// Round 12
// baseline (789.877 us; speedup 1.0000x reference)
//
#include <hip/hip_runtime.h>

typedef __bf16 bf16x8 __attribute__((ext_vector_type(8)));
typedef float f32x4 __attribute__((ext_vector_type(4)));
typedef unsigned short u16;
typedef unsigned int u32;
typedef u16 u16x8 __attribute__((ext_vector_type(8)));
typedef u16 u16x4 __attribute__((ext_vector_type(4)));

#define DEVI __device__ __forceinline__

static constexpr size_t R_ELEMS = (size_t)4096 * 4096;  // one 33.5MB bf16 region

DEVI u16 f2bf(float f) {
  u32 x = __float_as_uint(f);
  u32 r = x + 0x7FFFu + ((x >> 16) & 1u);
  return (u16)(r >> 16);
}
DEVI float bf2f(u16 u) { return __uint_as_float(((u32)u) << 16); }

#define GLOAD_LDS16(gp, lp)                                                     \
  __builtin_amdgcn_global_load_lds(                                             \
      (const __attribute__((address_space(1))) void*)(gp),                      \
      (__attribute__((address_space(3))) void*)(lp), 16, 0, 0)

#define MFMA16(a, b, c) __builtin_amdgcn_mfma_f32_16x16x32_bf16((a), (b), (c), 0, 0, 0)

// ---------------- fp32 -> bf16 convert ----------------
__global__ void k_cvt(const float* __restrict__ in, u16* __restrict__ out, int n8) {
  int i = blockIdx.x * blockDim.x + threadIdx.x;
  if (i >= n8) return;
  const float4* p = (const float4*)in + (size_t)i * 2;
  float4 a = p[0], b = p[1];
  u16x8 o;
  o[0] = f2bf(a.x); o[1] = f2bf(a.y); o[2] = f2bf(a.z); o[3] = f2bf(a.w);
  o[4] = f2bf(b.x); o[5] = f2bf(b.y); o[6] = f2bf(b.z); o[7] = f2bf(b.w);
  *((u16x8*)out + i) = o;
}

// ---------------- W fp32 [k][n] -> Wt bf16 [n][k] (r5-measured version) -----
__global__ void k_transpose_w(const float* __restrict__ W, u16* __restrict__ Wt) {
  __shared__ float t[64][65];
  int kb = blockIdx.x * 64, nb = blockIdx.y * 64;
  int tx = threadIdx.x, ty = threadIdx.y;
#pragma unroll
  for (int i = 0; i < 16; i++) {
    int r = i * 4 + ty;
    t[r][tx] = W[(size_t)(kb + r) * 4096 + nb + tx];
  }
  __syncthreads();
#pragma unroll
  for (int i = 0; i < 16; i++) {
    int r = i * 4 + ty;
    Wt[(size_t)(nb + r) * 4096 + kb + tx] = f2bf(t[tx][r]);
  }
}

// ---------------- GEMM: A[m][k] bf16 @ Bt[n][k] bf16 -> out (m97 structure) --
// OUTMODE 1: f32 row-major.  OUTMODE 2: bf16 Vt at (b,h,hd,s) from m=(b,s), n=(h,hd).
// 1D grid 1024 with bijective XCD-chunk swizzle (each XCD: 4 m-rows x 32 n).
template <int OUTMODE>
__global__ __launch_bounds__(256, 2) void k_gemm(const u16* __restrict__ A,
                                                 const u16* __restrict__ Bt,
                                                 void* __restrict__ outp) {
  __shared__ __attribute__((aligned(16))) u16 lA[128 * 64];
  __shared__ __attribute__((aligned(16))) u16 lB[128 * 64];
  const int tid = threadIdx.x;
  const int w = tid >> 6, lane = tid & 63;
  const int wr = w >> 1, wc = w & 1;
  const int bid = blockIdx.x;
  const int wg = (bid & 7) * 128 + (bid >> 3);
  const int m0 = (wg >> 5) * 128, n0 = (wg & 31) * 128;

  f32x4 acc[4][4];
#pragma unroll
  for (int i = 0; i < 4; i++)
#pragma unroll
    for (int j = 0; j < 4; j++) acc[i][j] = (f32x4){0.f, 0.f, 0.f, 0.f};

  const int srow = lane >> 3;                     // 0..7
  const int scol = ((lane & 7) ^ srow) * 8;       // pre-swizzled source col (u16)
  const u16* Abase = A + (size_t)(m0 + w * 32 + srow) * 4096 + scol;
  const u16* Bbase = Bt + (size_t)(n0 + w * 32 + srow) * 4096 + scol;
  u16* lAw = lA + w * 2048;
  u16* lBw = lB + w * 2048;

  const int lm = lane & 15;
  const int lk = lane >> 4;            // 0..3
  const int swz = (lane & 7) << 3;     // u16-unit swizzle for frag reads

  for (int kt = 0; kt < 64; ++kt) {
    __syncthreads();
#pragma unroll
    for (int i = 0; i < 4; ++i) {
      GLOAD_LDS16(Abase + (size_t)kt * 64 + (size_t)i * 8 * 4096, lAw + i * 512);
      GLOAD_LDS16(Bbase + (size_t)kt * 64 + (size_t)i * 8 * 4096, lBw + i * 512);
    }
    __syncthreads();
#pragma unroll
    for (int ks = 0; ks < 2; ++ks) {
      bf16x8 af[4], bfr[4];
      const int ce = (ks * 32 + lk * 8) ^ swz;
#pragma unroll
      for (int mi = 0; mi < 4; mi++)
        af[mi] = *(const bf16x8*)(lA + (wr * 64 + mi * 16 + lm) * 64 + ce);
#pragma unroll
      for (int ni = 0; ni < 4; ni++)
        bfr[ni] = *(const bf16x8*)(lB + (wc * 64 + ni * 16 + lm) * 64 + ce);
#pragma unroll
      for (int mi = 0; mi < 4; mi++)
#pragma unroll
        for (int ni = 0; ni < 4; ni++)
          acc[mi][ni] = MFMA16(af[mi], bfr[ni], acc[mi][ni]);
    }
  }

#pragma unroll
  for (int mi = 0; mi < 4; mi++) {
#pragma unroll
    for (int ni = 0; ni < 4; ni++) {
      const int mb = m0 + wr * 64 + mi * 16 + lk * 4;  // r=0 row
      const int n = n0 + wc * 64 + ni * 16 + lm;
      if (OUTMODE == 2) {
        // Vt (b,h,hd,s): lane's 4 consecutive s -> one 8B store
        u16x4 vt;
#pragma unroll
        for (int r = 0; r < 4; r++) vt[r] = f2bf(acc[mi][ni][r]);
        u16* o = (u16*)outp;
        *(u16x4*)&o[(size_t)((mb >> 11) * 16 + ((n >> 8) & 15)) * 524288 +
                    (size_t)(n & 255) * 2048 + (mb & 2047)] = vt;
      } else {
        float* o = (float*)outp;
#pragma unroll
        for (int r = 0; r < 4; r++) o[(size_t)(mb + r) * 4096 + n] = acc[mi][ni][r];
      }
    }
  }
}

// ---------------- fused Q+K GEMM with RoPE epilogue -------------------------
// A staged once, two B operands; rope applied to fp32 acc (hd<64) via
// shfl_xor(1) partner exchange; writes Q,K at (b,h,s,hd).
__global__ __launch_bounds__(256, 2) void k_gemm_qk(const u16* __restrict__ A,
                                                    const u16* __restrict__ Btq,
                                                    const u16* __restrict__ Btk,
                                                    const float* __restrict__ ep,
                                                    const int* __restrict__ pid,
                                                    u16* __restrict__ Qo,
                                                    u16* __restrict__ Ko) {
  __shared__ __attribute__((aligned(16))) u16 lA[128 * 64];
  __shared__ __attribute__((aligned(16))) u16 lBq[128 * 64];
  __shared__ __attribute__((aligned(16))) u16 lBk[128 * 64];
  const int tid = threadIdx.x;
  const int w = tid >> 6, lane = tid & 63;
  const int wr = w >> 1, wc = w & 1;
  const int bid = blockIdx.x;
  const int wg = (bid & 7) * 128 + (bid >> 3);
  const int m0 = (wg >> 5) * 128, n0 = (wg & 31) * 128;

  f32x4 accq[4][4], acck[4][4];
#pragma unroll
  for (int i = 0; i < 4; i++)
#pragma unroll
    for (int j = 0; j < 4; j++) {
      accq[i][j] = (f32x4){0.f, 0.f, 0.f, 0.f};
      acck[i][j] = (f32x4){0.f, 0.f, 0.f, 0.f};
    }

  const int srow = lane >> 3;
  const int scol = ((lane & 7) ^ srow) * 8;
  const u16* Abase = A + (size_t)(m0 + w * 32 + srow) * 4096 + scol;
  const u16* Bqb = Btq + (size_t)(n0 + w * 32 + srow) * 4096 + scol;
  const u16* Bkb = Btk + (size_t)(n0 + w * 32 + srow) * 4096 + scol;
  u16* lAw = lA + w * 2048;
  u16* lBqw = lBq + w * 2048;
  u16* lBkw = lBk + w * 2048;

  const int lm = lane & 15;
  const int lk = lane >> 4;
  const int swz = (lane & 7) << 3;

  for (int kt = 0; kt < 64; ++kt) {
    __syncthreads();
#pragma unroll
    for (int i = 0; i < 4; ++i) {
      GLOAD_LDS16(Abase + (size_t)kt * 64 + (size_t)i * 8 * 4096, lAw + i * 512);
      GLOAD_LDS16(Bqb + (size_t)kt * 64 + (size_t)i * 8 * 4096, lBqw + i * 512);
      GLOAD_LDS16(Bkb + (size_t)kt * 64 + (size_t)i * 8 * 4096, lBkw + i * 512);
    }
    __syncthreads();
#pragma unroll
    for (int ks = 0; ks < 2; ++ks) {
      bf16x8 af[4], bfr[4];
      const int ce = (ks * 32 + lk * 8) ^ swz;
#pragma unroll
      for (int mi = 0; mi < 4; mi++)
        af[mi] = *(const bf16x8*)(lA + (wr * 64 + mi * 16 + lm) * 64 + ce);
#pragma unroll
      for (int ni = 0; ni < 4; ni++)
        bfr[ni] = *(const bf16x8*)(lBq + (wc * 64 + ni * 16 + lm) * 64 + ce);
#pragma unroll
      for (int mi = 0; mi < 4; mi++)
#pragma unroll
        for (int ni = 0; ni < 4; ni++)
          accq[mi][ni] = MFMA16(af[mi], bfr[ni], accq[mi][ni]);
#pragma unroll
      for (int ni = 0; ni < 4; ni++)
        bfr[ni] = *(const bf16x8*)(lBk + (wc * 64 + ni * 16 + lm) * 64 + ce);
#pragma unroll
      for (int mi = 0; mi < 4; mi++)
#pragma unroll
        for (int ni = 0; ni < 4; ni++)
          acck[mi][ni] = MFMA16(af[mi], bfr[ni], acck[mi][ni]);
    }
  }

  // RoPE: hd = n & 255 < 64 only when n-block even and wc==0 (wave-uniform)
  const bool ropew = (((wg & 31) & 1) == 0) && (wc == 0);
  if (ropew) {
#pragma unroll
    for (int mi = 0; mi < 4; mi++) {
#pragma unroll
      for (int r = 0; r < 4; r++) {
        const int m = m0 + wr * 64 + mi * 16 + lk * 4 + r;
        const int pos = pid[(m >> 11) * 2048 + (m & 2047)];
#pragma unroll
        for (int ni = 0; ni < 4; ni++) {
          const int p = (ni * 16 + lm) >> 1;
          const float sn = ep[pos * 64 + p];
          const float cs = ep[pos * 64 + 32 + p];
          float q = accq[mi][ni][r], k = acck[mi][ni][r];
          float qp = __shfl_xor(q, 1, 64), kp = __shfl_xor(k, 1, 64);
          accq[mi][ni][r] = (lm & 1) ? (q * cs + qp * sn) : (q * cs - qp * sn);
          acck[mi][ni][r] = (lm & 1) ? (k * cs + kp * sn) : (k * cs - kp * sn);
        }
      }
    }
  }

#pragma unroll
  for (int mi = 0; mi < 4; mi++) {
#pragma unroll
    for (int ni = 0; ni < 4; ni++) {
#pragma unroll
      for (int r = 0; r < 4; r++) {
        int m = m0 + wr * 64 + mi * 16 + lk * 4 + r;
        int n = n0 + wc * 64 + ni * 16 + lm;
        size_t idx = (size_t)((m >> 11) * 16 + ((n >> 8) & 15)) * 524288 +
                     (size_t)(m & 2047) * 256 + (n & 255);
        Qo[idx] = f2bf(accq[mi][ni][r]);
        Ko[idx] = f2bf(acck[mi][ni][r]);
      }
    }
  }
}

// ---------------- causal flash attention v5 (best measured: 156us) ----------
__global__ __launch_bounds__(512, 2) void k_attn(const u16* __restrict__ Q,
                                                 const u16* __restrict__ K,
                                                 const u16* __restrict__ Vt,
                                                 const float* __restrict__ amask,
                                                 u16* __restrict__ AO) {
  __shared__ __attribute__((aligned(16))) u16 lK[2][64 * 256];   // 2x32KB [kv][hd] swz
  __shared__ __attribute__((aligned(16))) u16 lV[2][256 * 64];   // 2x32KB [d][kv] swz
  __shared__ __attribute__((aligned(16))) u16 lP[8][16 * 64];    // 16KB per-wave P

  const int tid = threadIdx.x, w = tid >> 6, lane = tid & 63;
  const int wg = blockIdx.x;
  const int bh = wg & 31;
  const int qt = (wg < 256) ? (15 - (wg >> 5)) : ((wg - 256) >> 5);
  const int b = bh >> 4;
  const int lm = lane & 15, lk = lane >> 4;
  const size_t head = (size_t)bh * (2048 * 256);
  const int q0 = qt * 128 + w * 16;
  const int swzl = (lane & 7) << 3;

  const int kreg_row = (lane >> 5);
  const int kcol = (lane & 31) * 8;
  const int vreg_row = (lane >> 3);
  const int vcol = (lane & 7) * 8;

#define ASTAGE(t)                                                                \
  {                                                                              \
    const int bb_ = (t) & 1;                                                     \
    const int kv0_ = (t) * 64;                                                   \
    _Pragma("unroll") for (int i_ = 0; i_ < 4; i_++) {                           \
      const int reg_ = w + i_ * 8;                                               \
      const int krow_ = reg_ * 2 + kreg_row;                                     \
      GLOAD_LDS16(K + head + (size_t)(kv0_ + krow_) * 256 +                      \
                      (kcol ^ ((krow_ & 7) << 3)),                               \
                  &lK[bb_][reg_ * 512 + lane * 8]);                              \
      const int vrow_ = reg_ * 8 + vreg_row;                                     \
      GLOAD_LDS16(Vt + head + (size_t)vrow_ * 2048 + kv0_ +                      \
                      (vcol ^ ((vrow_ & 7) << 3)),                               \
                  &lV[bb_][reg_ * 512 + lane * 8]);                              \
    }                                                                            \
  }

  bf16x8 qf[8];
#pragma unroll
  for (int c = 0; c < 8; c++)
    qf[c] = *(const bf16x8*)(Q + head + (size_t)(q0 + lm) * 256 + c * 32 + lk * 8);

  f32x4 o[16];
#pragma unroll
  for (int i = 0; i < 16; i++) o[i] = (f32x4){0.f, 0.f, 0.f, 0.f};
  float m_s = -__builtin_inff();
  float l_s = 0.f;

  const int ntiles = 2 * qt + 2;
  ASTAGE(0);

  for (int t = 0; t < ntiles; ++t) {
    const int kv0 = t * 64;
    const int bb = t & 1;
    float4 amq[4];
#pragma unroll
    for (int kb = 0; kb < 4; kb++)
      amq[kb] = *(const float4*)(amask + b * 2048 + kv0 + kb * 16 + lk * 4);
    if (t + 1 < ntiles) {
      ASTAGE(t + 1);
      asm volatile("s_waitcnt vmcnt(8)" ::: "memory");
    } else {
      asm volatile("s_waitcnt vmcnt(0)" ::: "memory");
    }
    __builtin_amdgcn_s_barrier();

    if (q0 + 15 >= kv0) {
      const u16* lKb = lK[bb];
      const u16* lVb = lV[bb];

      float sx[4][4];
      __builtin_amdgcn_s_setprio(1);
#pragma unroll
      for (int kb = 0; kb < 4; kb++) {
        f32x4 sa = (f32x4){0.f, 0.f, 0.f, 0.f};
        const int kvr = kb * 16 + lm;
#pragma unroll
        for (int c = 0; c < 8; c++) {
          bf16x8 kf = *(const bf16x8*)(lKb + kvr * 256 + ((c * 32 + lk * 8) ^ swzl));
          sa = __builtin_amdgcn_mfma_f32_16x16x32_bf16(kf, qf[c], sa, 0, 0, 0);
        }
#pragma unroll
        for (int r = 0; r < 4; r++)
          sx[kb][r] = sa[r] * 0.0625f + ((const float*)&amq[kb])[r];
      }
      __builtin_amdgcn_s_setprio(0);

      const int q_abs = q0 + lm;
      float tm = -__builtin_inff();
#pragma unroll
      for (int kb = 0; kb < 4; kb++)
#pragma unroll
        for (int r = 0; r < 4; r++) {
          bool valid = (kv0 + kb * 16 + lk * 4 + r) <= q_abs;
          tm = fmaxf(tm, valid ? sx[kb][r] : -__builtin_inff());
        }
      tm = fmaxf(tm, __shfl_xor(tm, 16, 64));
      tm = fmaxf(tm, __shfl_xor(tm, 32, 64));

      if (!__all(tm <= m_s + 8.0f)) {
        float mnew = fmaxf(m_s, tm);
        float alpha = __expf(m_s - mnew);
        m_s = mnew;
        l_s *= alpha;
        float af0 = __shfl(alpha, lk * 4 + 0, 64);
        float af1 = __shfl(alpha, lk * 4 + 1, 64);
        float af2 = __shfl(alpha, lk * 4 + 2, 64);
        float af3 = __shfl(alpha, lk * 4 + 3, 64);
#pragma unroll
        for (int dblk = 0; dblk < 16; dblk++) {
          o[dblk][0] *= af0; o[dblk][1] *= af1;
          o[dblk][2] *= af2; o[dblk][3] *= af3;
        }
      }

      float psum = 0.f;
#pragma unroll
      for (int kb = 0; kb < 4; kb++) {
        u16x4 ph;
#pragma unroll
        for (int r = 0; r < 4; r++) {
          bool valid = (kv0 + kb * 16 + lk * 4 + r) <= q_abs;
          float p = valid ? __expf(sx[kb][r] - m_s) : 0.f;
          psum += p;
          ph[r] = f2bf(p);
        }
        *(u16x4*)(&lP[w][lm * 64 + ((kb * 16 + lk * 4) ^ swzl)]) = ph;
      }
      psum += __shfl_xor(psum, 16, 64);
      psum += __shfl_xor(psum, 32, 64);
      l_s += psum;

      bf16x8 pa[2];
#pragma unroll
      for (int kh = 0; kh < 2; kh++)
        pa[kh] = *(const bf16x8*)(&lP[w][lm * 64 + ((lk * 8 + kh * 32) ^ swzl)]);
      __builtin_amdgcn_s_setprio(1);
#pragma unroll
      for (int dblk = 0; dblk < 16; dblk++) {
        const int dr = dblk * 16 + lm;
#pragma unroll
        for (int kh = 0; kh < 2; kh++) {
          bf16x8 vf = *(const bf16x8*)(lVb + dr * 64 + ((lk * 8 + kh * 32) ^ swzl));
          o[dblk] = __builtin_amdgcn_mfma_f32_16x16x32_bf16(pa[kh], vf, o[dblk], 0, 0, 0);
        }
      }
      __builtin_amdgcn_s_setprio(0);
    }
    __builtin_amdgcn_s_barrier();
  }
#undef ASTAGE

  float linv[4];
#pragma unroll
  for (int r = 0; r < 4; r++) linv[r] = 1.0f / __shfl(l_s, lk * 4 + r, 64);
#pragma unroll
  for (int r = 0; r < 4; r++) {
    const int s_abs = q0 + lk * 4 + r;
#pragma unroll
    for (int dblk = 0; dblk < 16; dblk++) {
      int d = (bh & 15) * 256 + dblk * 16 + lm;
      AO[((size_t)b * 2048 + s_abs) * 4096 + d] = f2bf(o[dblk][r] * linv[r]);
    }
  }
}

extern "C" void kernel_launch(void* const* d_in, const int* in_sizes, int n_in,
                              void* d_out, int out_size, void* d_ws, size_t ws_size,
                              hipStream_t stream) {
  (void)in_sizes; (void)n_in; (void)out_size; (void)ws_size;
  const float* hs = (const float*)d_in[0];
  const float* Wq = (const float*)d_in[1];
  const float* Wk = (const float*)d_in[2];
  const float* Wv = (const float*)d_in[3];
  const float* Wo = (const float*)d_in[4];
  const float* ep = (const float*)d_in[5];
  const float* am = (const float*)d_in[6];
  const int* pid = (const int*)d_in[7];

  u16* r0 = (u16*)d_ws;        // hidden bf16, later AO
  u16* r1 = r0 + R_ELEMS;      // Wt_q -> Wt_v -> Wt_o
  u16* r2 = r1 + R_ELEMS;      // Wt_k -> Vt
  u16* r3 = r2 + R_ELEMS;      // Q (b,h,s,hd), rope'd
  u16* r4 = r3 + R_ELEMS;      // K (b,h,s,hd), rope'd
  float* out = (float*)d_out;

  dim3 b256(256), b512(512), bT(64, 4);
  k_cvt<<<dim3(8192), b256, 0, stream>>>(hs, r0, 16777216 / 8);

  k_transpose_w<<<dim3(64, 64), bT, 0, stream>>>(Wq, r1);
  k_transpose_w<<<dim3(64, 64), bT, 0, stream>>>(Wk, r2);
  k_gemm_qk<<<dim3(1024), b256, 0, stream>>>(r0, r1, r2, ep, pid, r3, r4);

  k_transpose_w<<<dim3(64, 64), bT, 0, stream>>>(Wv, r1);
  k_gemm<2><<<dim3(1024), b256, 0, stream>>>(r0, r1, r2);     // Vt -> r2

  k_attn<<<dim3(512), b512, 0, stream>>>(r3, r4, r2, am, r0); // AO -> r0

  k_transpose_w<<<dim3(64, 64), bT, 0, stream>>>(Wo, r1);
  k_gemm<1><<<dim3(1024), b256, 0, stream>>>(r0, r1, out);
}

// Round 13
// 727.475 us; speedup vs baseline: 1.0858x; 1.0858x over previous
//
#include <hip/hip_runtime.h>

typedef __bf16 bf16x8 __attribute__((ext_vector_type(8)));
typedef float f32x4 __attribute__((ext_vector_type(4)));
typedef unsigned short u16;
typedef unsigned int u32;
typedef u16 u16x8 __attribute__((ext_vector_type(8)));
typedef u16 u16x4 __attribute__((ext_vector_type(4)));

#define DEVI __device__ __forceinline__

static constexpr size_t R_ELEMS = (size_t)4096 * 4096;  // one 33.5MB bf16 region

DEVI u16 f2bf(float f) {
  u32 x = __float_as_uint(f);
  u32 r = x + 0x7FFFu + ((x >> 16) & 1u);
  return (u16)(r >> 16);
}
DEVI float bf2f(u16 u) { return __uint_as_float(((u32)u) << 16); }

#define GLOAD_LDS16(gp, lp)                                                     \
  __builtin_amdgcn_global_load_lds(                                             \
      (const __attribute__((address_space(1))) void*)(gp),                      \
      (__attribute__((address_space(3))) void*)(lp), 16, 0, 0)

#define MFMA16(a, b, c) __builtin_amdgcn_mfma_f32_16x16x32_bf16((a), (b), (c), 0, 0, 0)

// ---------------- fp32 -> bf16 convert ----------------
__global__ void k_cvt(const float* __restrict__ in, u16* __restrict__ out, int n8) {
  int i = blockIdx.x * blockDim.x + threadIdx.x;
  if (i >= n8) return;
  const float4* p = (const float4*)in + (size_t)i * 2;
  float4 a = p[0], b = p[1];
  u16x8 o;
  o[0] = f2bf(a.x); o[1] = f2bf(a.y); o[2] = f2bf(a.z); o[3] = f2bf(a.w);
  o[4] = f2bf(b.x); o[5] = f2bf(b.y); o[6] = f2bf(b.z); o[7] = f2bf(b.w);
  *((u16x8*)out + i) = o;
}

// ---------------- W fp32 [k][n] -> Wt bf16 [n][k] (r5-measured version) -----
__global__ void k_transpose_w(const float* __restrict__ W, u16* __restrict__ Wt) {
  __shared__ float t[64][65];
  int kb = blockIdx.x * 64, nb = blockIdx.y * 64;
  int tx = threadIdx.x, ty = threadIdx.y;
#pragma unroll
  for (int i = 0; i < 16; i++) {
    int r = i * 4 + ty;
    t[r][tx] = W[(size_t)(kb + r) * 4096 + nb + tx];
  }
  __syncthreads();
#pragma unroll
  for (int i = 0; i < 16; i++) {
    int r = i * 4 + ty;
    Wt[(size_t)(nb + r) * 4096 + kb + tx] = f2bf(t[tx][r]);
  }
}

// ---------------- GEMM: A[m][k] bf16 @ Bt[n][k] bf16 -> out (m97 structure) --
// OUTMODE 1: f32 row-major.  OUTMODE 2: bf16 Vt at (b,h,hd,s) from m=(b,s), n=(h,hd).
// 2D grid (x=n fastest) — measured-best dispatch ordering.
template <int OUTMODE>
__global__ __launch_bounds__(256, 2) void k_gemm(const u16* __restrict__ A,
                                                 const u16* __restrict__ Bt,
                                                 void* __restrict__ outp) {
  __shared__ __attribute__((aligned(16))) u16 lA[128 * 64];
  __shared__ __attribute__((aligned(16))) u16 lB[128 * 64];
  const int tid = threadIdx.x;
  const int w = tid >> 6, lane = tid & 63;
  const int wr = w >> 1, wc = w & 1;
  const int m0 = blockIdx.y * 128, n0 = blockIdx.x * 128;

  f32x4 acc[4][4];
#pragma unroll
  for (int i = 0; i < 4; i++)
#pragma unroll
    for (int j = 0; j < 4; j++) acc[i][j] = (f32x4){0.f, 0.f, 0.f, 0.f};

  const int srow = lane >> 3;                     // 0..7
  const int scol = ((lane & 7) ^ srow) * 8;       // pre-swizzled source col (u16)
  const u16* Abase = A + (size_t)(m0 + w * 32 + srow) * 4096 + scol;
  const u16* Bbase = Bt + (size_t)(n0 + w * 32 + srow) * 4096 + scol;
  u16* lAw = lA + w * 2048;
  u16* lBw = lB + w * 2048;

  const int lm = lane & 15;
  const int lk = lane >> 4;            // 0..3
  const int swz = (lane & 7) << 3;     // u16-unit swizzle for frag reads

  for (int kt = 0; kt < 64; ++kt) {
    __syncthreads();
#pragma unroll
    for (int i = 0; i < 4; ++i) {
      GLOAD_LDS16(Abase + (size_t)kt * 64 + (size_t)i * 8 * 4096, lAw + i * 512);
      GLOAD_LDS16(Bbase + (size_t)kt * 64 + (size_t)i * 8 * 4096, lBw + i * 512);
    }
    __syncthreads();
#pragma unroll
    for (int ks = 0; ks < 2; ++ks) {
      bf16x8 af[4], bfr[4];
      const int ce = (ks * 32 + lk * 8) ^ swz;
#pragma unroll
      for (int mi = 0; mi < 4; mi++)
        af[mi] = *(const bf16x8*)(lA + (wr * 64 + mi * 16 + lm) * 64 + ce);
#pragma unroll
      for (int ni = 0; ni < 4; ni++)
        bfr[ni] = *(const bf16x8*)(lB + (wc * 64 + ni * 16 + lm) * 64 + ce);
#pragma unroll
      for (int mi = 0; mi < 4; mi++)
#pragma unroll
        for (int ni = 0; ni < 4; ni++)
          acc[mi][ni] = MFMA16(af[mi], bfr[ni], acc[mi][ni]);
    }
  }

#pragma unroll
  for (int mi = 0; mi < 4; mi++) {
#pragma unroll
    for (int ni = 0; ni < 4; ni++) {
      const int mb = m0 + wr * 64 + mi * 16 + lk * 4;  // r=0 row
      const int n = n0 + wc * 64 + ni * 16 + lm;
      if (OUTMODE == 2) {
        // Vt (b,h,hd,s): lane's 4 consecutive s -> one 8B store
        u16x4 vt;
#pragma unroll
        for (int r = 0; r < 4; r++) vt[r] = f2bf(acc[mi][ni][r]);
        u16* o = (u16*)outp;
        *(u16x4*)&o[(size_t)((mb >> 11) * 16 + ((n >> 8) & 15)) * 524288 +
                    (size_t)(n & 255) * 2048 + (mb & 2047)] = vt;
      } else {
        float* o = (float*)outp;
#pragma unroll
        for (int r = 0; r < 4; r++) o[(size_t)(mb + r) * 4096 + n] = acc[mi][ni][r];
      }
    }
  }
}

// ---------------- fused Q+K GEMM with RoPE epilogue -------------------------
// A staged once, two B operands; rope applied to fp32 acc (hd<64) via
// shfl_xor(1) partner exchange; writes Q,K at (b,h,s,hd). 2D grid.
__global__ __launch_bounds__(256, 2) void k_gemm_qk(const u16* __restrict__ A,
                                                    const u16* __restrict__ Btq,
                                                    const u16* __restrict__ Btk,
                                                    const float* __restrict__ ep,
                                                    const int* __restrict__ pid,
                                                    u16* __restrict__ Qo,
                                                    u16* __restrict__ Ko) {
  __shared__ __attribute__((aligned(16))) u16 lA[128 * 64];
  __shared__ __attribute__((aligned(16))) u16 lBq[128 * 64];
  __shared__ __attribute__((aligned(16))) u16 lBk[128 * 64];
  const int tid = threadIdx.x;
  const int w = tid >> 6, lane = tid & 63;
  const int wr = w >> 1, wc = w & 1;
  const int m0 = blockIdx.y * 128, n0 = blockIdx.x * 128;

  f32x4 accq[4][4], acck[4][4];
#pragma unroll
  for (int i = 0; i < 4; i++)
#pragma unroll
    for (int j = 0; j < 4; j++) {
      accq[i][j] = (f32x4){0.f, 0.f, 0.f, 0.f};
      acck[i][j] = (f32x4){0.f, 0.f, 0.f, 0.f};
    }

  const int srow = lane >> 3;
  const int scol = ((lane & 7) ^ srow) * 8;
  const u16* Abase = A + (size_t)(m0 + w * 32 + srow) * 4096 + scol;
  const u16* Bqb = Btq + (size_t)(n0 + w * 32 + srow) * 4096 + scol;
  const u16* Bkb = Btk + (size_t)(n0 + w * 32 + srow) * 4096 + scol;
  u16* lAw = lA + w * 2048;
  u16* lBqw = lBq + w * 2048;
  u16* lBkw = lBk + w * 2048;

  const int lm = lane & 15;
  const int lk = lane >> 4;
  const int swz = (lane & 7) << 3;

  for (int kt = 0; kt < 64; ++kt) {
    __syncthreads();
#pragma unroll
    for (int i = 0; i < 4; ++i) {
      GLOAD_LDS16(Abase + (size_t)kt * 64 + (size_t)i * 8 * 4096, lAw + i * 512);
      GLOAD_LDS16(Bqb + (size_t)kt * 64 + (size_t)i * 8 * 4096, lBqw + i * 512);
      GLOAD_LDS16(Bkb + (size_t)kt * 64 + (size_t)i * 8 * 4096, lBkw + i * 512);
    }
    __syncthreads();
#pragma unroll
    for (int ks = 0; ks < 2; ++ks) {
      bf16x8 af[4], bfr[4];
      const int ce = (ks * 32 + lk * 8) ^ swz;
#pragma unroll
      for (int mi = 0; mi < 4; mi++)
        af[mi] = *(const bf16x8*)(lA + (wr * 64 + mi * 16 + lm) * 64 + ce);
#pragma unroll
      for (int ni = 0; ni < 4; ni++)
        bfr[ni] = *(const bf16x8*)(lBq + (wc * 64 + ni * 16 + lm) * 64 + ce);
#pragma unroll
      for (int mi = 0; mi < 4; mi++)
#pragma unroll
        for (int ni = 0; ni < 4; ni++)
          accq[mi][ni] = MFMA16(af[mi], bfr[ni], accq[mi][ni]);
#pragma unroll
      for (int ni = 0; ni < 4; ni++)
        bfr[ni] = *(const bf16x8*)(lBk + (wc * 64 + ni * 16 + lm) * 64 + ce);
#pragma unroll
      for (int mi = 0; mi < 4; mi++)
#pragma unroll
        for (int ni = 0; ni < 4; ni++)
          acck[mi][ni] = MFMA16(af[mi], bfr[ni], acck[mi][ni]);
    }
  }

  // RoPE: hd = n & 255 < 64 only when n-block even and wc==0 (wave-uniform)
  const bool ropew = ((blockIdx.x & 1) == 0) && (wc == 0);
  if (ropew) {
#pragma unroll
    for (int mi = 0; mi < 4; mi++) {
#pragma unroll
      for (int r = 0; r < 4; r++) {
        const int m = m0 + wr * 64 + mi * 16 + lk * 4 + r;
        const int pos = pid[(m >> 11) * 2048 + (m & 2047)];
#pragma unroll
        for (int ni = 0; ni < 4; ni++) {
          const int p = (ni * 16 + lm) >> 1;
          const float sn = ep[pos * 64 + p];
          const float cs = ep[pos * 64 + 32 + p];
          float q = accq[mi][ni][r], k = acck[mi][ni][r];
          float qp = __shfl_xor(q, 1, 64), kp = __shfl_xor(k, 1, 64);
          accq[mi][ni][r] = (lm & 1) ? (q * cs + qp * sn) : (q * cs - qp * sn);
          acck[mi][ni][r] = (lm & 1) ? (k * cs + kp * sn) : (k * cs - kp * sn);
        }
      }
    }
  }

#pragma unroll
  for (int mi = 0; mi < 4; mi++) {
#pragma unroll
    for (int ni = 0; ni < 4; ni++) {
#pragma unroll
      for (int r = 0; r < 4; r++) {
        int m = m0 + wr * 64 + mi * 16 + lk * 4 + r;
        int n = n0 + wc * 64 + ni * 16 + lm;
        size_t idx = (size_t)((m >> 11) * 16 + ((n >> 8) & 15)) * 524288 +
                     (size_t)(m & 2047) * 256 + (n & 255);
        Qo[idx] = f2bf(accq[mi][ni][r]);
        Ko[idx] = f2bf(acck[mi][ni][r]);
      }
    }
  }
}

// ---------------- causal flash attention v5 (best measured: 156us) ----------
__global__ __launch_bounds__(512, 2) void k_attn(const u16* __restrict__ Q,
                                                 const u16* __restrict__ K,
                                                 const u16* __restrict__ Vt,
                                                 const float* __restrict__ amask,
                                                 u16* __restrict__ AO) {
  __shared__ __attribute__((aligned(16))) u16 lK[2][64 * 256];   // 2x32KB [kv][hd] swz
  __shared__ __attribute__((aligned(16))) u16 lV[2][256 * 64];   // 2x32KB [d][kv] swz
  __shared__ __attribute__((aligned(16))) u16 lP[8][16 * 64];    // 16KB per-wave P

  const int tid = threadIdx.x, w = tid >> 6, lane = tid & 63;
  const int wg = blockIdx.x;
  const int bh = wg & 31;
  const int qt = (wg < 256) ? (15 - (wg >> 5)) : ((wg - 256) >> 5);
  const int b = bh >> 4;
  const int lm = lane & 15, lk = lane >> 4;
  const size_t head = (size_t)bh * (2048 * 256);
  const int q0 = qt * 128 + w * 16;
  const int swzl = (lane & 7) << 3;

  const int kreg_row = (lane >> 5);
  const int kcol = (lane & 31) * 8;
  const int vreg_row = (lane >> 3);
  const int vcol = (lane & 7) * 8;

#define ASTAGE(t)                                                                \
  {                                                                              \
    const int bb_ = (t) & 1;                                                     \
    const int kv0_ = (t) * 64;                                                   \
    _Pragma("unroll") for (int i_ = 0; i_ < 4; i_++) {                           \
      const int reg_ = w + i_ * 8;                                               \
      const int krow_ = reg_ * 2 + kreg_row;                                     \
      GLOAD_LDS16(K + head + (size_t)(kv0_ + krow_) * 256 +                      \
                      (kcol ^ ((krow_ & 7) << 3)),                               \
                  &lK[bb_][reg_ * 512 + lane * 8]);                              \
      const int vrow_ = reg_ * 8 + vreg_row;                                     \
      GLOAD_LDS16(Vt + head + (size_t)vrow_ * 2048 + kv0_ +                      \
                      (vcol ^ ((vrow_ & 7) << 3)),                               \
                  &lV[bb_][reg_ * 512 + lane * 8]);                              \
    }                                                                            \
  }

  bf16x8 qf[8];
#pragma unroll
  for (int c = 0; c < 8; c++)
    qf[c] = *(const bf16x8*)(Q + head + (size_t)(q0 + lm) * 256 + c * 32 + lk * 8);

  f32x4 o[16];
#pragma unroll
  for (int i = 0; i < 16; i++) o[i] = (f32x4){0.f, 0.f, 0.f, 0.f};
  float m_s = -__builtin_inff();
  float l_s = 0.f;

  const int ntiles = 2 * qt + 2;
  ASTAGE(0);

  for (int t = 0; t < ntiles; ++t) {
    const int kv0 = t * 64;
    const int bb = t & 1;
    float4 amq[4];
#pragma unroll
    for (int kb = 0; kb < 4; kb++)
      amq[kb] = *(const float4*)(amask + b * 2048 + kv0 + kb * 16 + lk * 4);
    if (t + 1 < ntiles) {
      ASTAGE(t + 1);
      asm volatile("s_waitcnt vmcnt(8)" ::: "memory");
    } else {
      asm volatile("s_waitcnt vmcnt(0)" ::: "memory");
    }
    __builtin_amdgcn_s_barrier();

    if (q0 + 15 >= kv0) {
      const u16* lKb = lK[bb];
      const u16* lVb = lV[bb];

      float sx[4][4];
      __builtin_amdgcn_s_setprio(1);
#pragma unroll
      for (int kb = 0; kb < 4; kb++) {
        f32x4 sa = (f32x4){0.f, 0.f, 0.f, 0.f};
        const int kvr = kb * 16 + lm;
#pragma unroll
        for (int c = 0; c < 8; c++) {
          bf16x8 kf = *(const bf16x8*)(lKb + kvr * 256 + ((c * 32 + lk * 8) ^ swzl));
          sa = __builtin_amdgcn_mfma_f32_16x16x32_bf16(kf, qf[c], sa, 0, 0, 0);
        }
#pragma unroll
        for (int r = 0; r < 4; r++)
          sx[kb][r] = sa[r] * 0.0625f + ((const float*)&amq[kb])[r];
      }
      __builtin_amdgcn_s_setprio(0);

      const int q_abs = q0 + lm;
      float tm = -__builtin_inff();
#pragma unroll
      for (int kb = 0; kb < 4; kb++)
#pragma unroll
        for (int r = 0; r < 4; r++) {
          bool valid = (kv0 + kb * 16 + lk * 4 + r) <= q_abs;
          tm = fmaxf(tm, valid ? sx[kb][r] : -__builtin_inff());
        }
      tm = fmaxf(tm, __shfl_xor(tm, 16, 64));
      tm = fmaxf(tm, __shfl_xor(tm, 32, 64));

      if (!__all(tm <= m_s + 8.0f)) {
        float mnew = fmaxf(m_s, tm);
        float alpha = __expf(m_s - mnew);
        m_s = mnew;
        l_s *= alpha;
        float af0 = __shfl(alpha, lk * 4 + 0, 64);
        float af1 = __shfl(alpha, lk * 4 + 1, 64);
        float af2 = __shfl(alpha, lk * 4 + 2, 64);
        float af3 = __shfl(alpha, lk * 4 + 3, 64);
#pragma unroll
        for (int dblk = 0; dblk < 16; dblk++) {
          o[dblk][0] *= af0; o[dblk][1] *= af1;
          o[dblk][2] *= af2; o[dblk][3] *= af3;
        }
      }

      float psum = 0.f;
#pragma unroll
      for (int kb = 0; kb < 4; kb++) {
        u16x4 ph;
#pragma unroll
        for (int r = 0; r < 4; r++) {
          bool valid = (kv0 + kb * 16 + lk * 4 + r) <= q_abs;
          float p = valid ? __expf(sx[kb][r] - m_s) : 0.f;
          psum += p;
          ph[r] = f2bf(p);
        }
        *(u16x4*)(&lP[w][lm * 64 + ((kb * 16 + lk * 4) ^ swzl)]) = ph;
      }
      psum += __shfl_xor(psum, 16, 64);
      psum += __shfl_xor(psum, 32, 64);
      l_s += psum;

      bf16x8 pa[2];
#pragma unroll
      for (int kh = 0; kh < 2; kh++)
        pa[kh] = *(const bf16x8*)(&lP[w][lm * 64 + ((lk * 8 + kh * 32) ^ swzl)]);
      __builtin_amdgcn_s_setprio(1);
#pragma unroll
      for (int dblk = 0; dblk < 16; dblk++) {
        const int dr = dblk * 16 + lm;
#pragma unroll
        for (int kh = 0; kh < 2; kh++) {
          bf16x8 vf = *(const bf16x8*)(lVb + dr * 64 + ((lk * 8 + kh * 32) ^ swzl));
          o[dblk] = __builtin_amdgcn_mfma_f32_16x16x32_bf16(pa[kh], vf, o[dblk], 0, 0, 0);
        }
      }
      __builtin_amdgcn_s_setprio(0);
    }
    __builtin_amdgcn_s_barrier();
  }
#undef ASTAGE

  float linv[4];
#pragma unroll
  for (int r = 0; r < 4; r++) linv[r] = 1.0f / __shfl(l_s, lk * 4 + r, 64);
#pragma unroll
  for (int r = 0; r < 4; r++) {
    const int s_abs = q0 + lk * 4 + r;
#pragma unroll
    for (int dblk = 0; dblk < 16; dblk++) {
      int d = (bh & 15) * 256 + dblk * 16 + lm;
      AO[((size_t)b * 2048 + s_abs) * 4096 + d] = f2bf(o[dblk][r] * linv[r]);
    }
  }
}

extern "C" void kernel_launch(void* const* d_in, const int* in_sizes, int n_in,
                              void* d_out, int out_size, void* d_ws, size_t ws_size,
                              hipStream_t stream) {
  (void)in_sizes; (void)n_in; (void)out_size; (void)ws_size;
  const float* hs = (const float*)d_in[0];
  const float* Wq = (const float*)d_in[1];
  const float* Wk = (const float*)d_in[2];
  const float* Wv = (const float*)d_in[3];
  const float* Wo = (const float*)d_in[4];
  const float* ep = (const float*)d_in[5];
  const float* am = (const float*)d_in[6];
  const int* pid = (const int*)d_in[7];

  u16* r0 = (u16*)d_ws;        // hidden bf16, later AO
  u16* r1 = r0 + R_ELEMS;      // Wt_q -> Wt_v -> Wt_o
  u16* r2 = r1 + R_ELEMS;      // Wt_k -> Vt
  u16* r3 = r2 + R_ELEMS;      // Q (b,h,s,hd), rope'd
  u16* r4 = r3 + R_ELEMS;      // K (b,h,s,hd), rope'd
  float* out = (float*)d_out;

  dim3 b256(256), b512(512), bT(64, 4);
  k_cvt<<<dim3(8192), b256, 0, stream>>>(hs, r0, 16777216 / 8);

  k_transpose_w<<<dim3(64, 64), bT, 0, stream>>>(Wq, r1);
  k_transpose_w<<<dim3(64, 64), bT, 0, stream>>>(Wk, r2);
  k_gemm_qk<<<dim3(32, 32), b256, 0, stream>>>(r0, r1, r2, ep, pid, r3, r4);

  k_transpose_w<<<dim3(64, 64), bT, 0, stream>>>(Wv, r1);
  k_gemm<2><<<dim3(32, 32), b256, 0, stream>>>(r0, r1, r2);   // Vt -> r2

  k_attn<<<dim3(512), b512, 0, stream>>>(r3, r4, r2, am, r0); // AO -> r0

  k_transpose_w<<<dim3(64, 64), bT, 0, stream>>>(Wo, r1);
  k_gemm<1><<<dim3(32, 32), b256, 0, stream>>>(r0, r1, out);
}

// Round 14
// 701.920 us; speedup vs baseline: 1.1253x; 1.0364x over previous
//
#include <hip/hip_runtime.h>

typedef __bf16 bf16x8 __attribute__((ext_vector_type(8)));
typedef float f32x4 __attribute__((ext_vector_type(4)));
typedef unsigned short u16;
typedef unsigned int u32;
typedef u16 u16x8 __attribute__((ext_vector_type(8)));
typedef u16 u16x4 __attribute__((ext_vector_type(4)));

#define DEVI __device__ __forceinline__

static constexpr size_t R_ELEMS = (size_t)4096 * 4096;  // one 33.5MB bf16 region

DEVI u16 f2bf(float f) {
  u32 x = __float_as_uint(f);
  u32 r = x + 0x7FFFu + ((x >> 16) & 1u);
  return (u16)(r >> 16);
}
DEVI float bf2f(u16 u) { return __uint_as_float(((u32)u) << 16); }

#define GLOAD_LDS16(gp, lp)                                                     \
  __builtin_amdgcn_global_load_lds(                                             \
      (const __attribute__((address_space(1))) void*)(gp),                      \
      (__attribute__((address_space(3))) void*)(lp), 16, 0, 0)

#define MFMA16(a, b, c) __builtin_amdgcn_mfma_f32_16x16x32_bf16((a), (b), (c), 0, 0, 0)

// ---------------- fp32 -> bf16 convert ----------------
__global__ void k_cvt(const float* __restrict__ in, u16* __restrict__ out, int n8) {
  int i = blockIdx.x * blockDim.x + threadIdx.x;
  if (i >= n8) return;
  const float4* p = (const float4*)in + (size_t)i * 2;
  float4 a = p[0], b = p[1];
  u16x8 o;
  o[0] = f2bf(a.x); o[1] = f2bf(a.y); o[2] = f2bf(a.z); o[3] = f2bf(a.w);
  o[4] = f2bf(b.x); o[5] = f2bf(b.y); o[6] = f2bf(b.z); o[7] = f2bf(b.w);
  *((u16x8*)out + i) = o;
}

// ---------------- W fp32 [k][n] -> Wt bf16 [n][k] (r5-measured version) -----
__global__ void k_transpose_w(const float* __restrict__ W, u16* __restrict__ Wt) {
  __shared__ float t[64][65];
  int kb = blockIdx.x * 64, nb = blockIdx.y * 64;
  int tx = threadIdx.x, ty = threadIdx.y;
#pragma unroll
  for (int i = 0; i < 16; i++) {
    int r = i * 4 + ty;
    t[r][tx] = W[(size_t)(kb + r) * 4096 + nb + tx];
  }
  __syncthreads();
#pragma unroll
  for (int i = 0; i < 16; i++) {
    int r = i * 4 + ty;
    Wt[(size_t)(nb + r) * 4096 + kb + tx] = f2bf(t[tx][r]);
  }
}

// ------- GEMM v2: 128m x 256n block, 4 waves, wave tile 64x128 --------------
// A[m][k] bf16 @ Bt[n][k] bf16. 12 ds_reads per 32 MFMA per wave K-step
// (25% fewer LDS reads/FLOP than the 128x128 tile).
// OUTMODE 1: f32 row-major.  OUTMODE 2: bf16 Vt at (b,h,hd,s) from m=(b,s), n=(h,hd).
template <int OUTMODE>
__global__ __launch_bounds__(256, 2) void k_gemm(const u16* __restrict__ A,
                                                 const u16* __restrict__ Bt,
                                                 void* __restrict__ outp) {
  __shared__ __attribute__((aligned(16))) u16 lA[128 * 64];  // 16 KB
  __shared__ __attribute__((aligned(16))) u16 lB[256 * 64];  // 32 KB
  const int tid = threadIdx.x;
  const int w = tid >> 6, lane = tid & 63;
  const int wr = w >> 1, wc = w & 1;
  const int m0 = blockIdx.y * 128, n0 = blockIdx.x * 256;

  f32x4 acc[4][8];
#pragma unroll
  for (int i = 0; i < 4; i++)
#pragma unroll
    for (int j = 0; j < 8; j++) acc[i][j] = (f32x4){0.f, 0.f, 0.f, 0.f};

  const int srow = lane >> 3;                     // 0..7
  const int scol = ((lane & 7) ^ srow) * 8;       // pre-swizzled source col (u16)
  const u16* Abase = A + (size_t)(m0 + w * 32 + srow) * 4096 + scol;
  const u16* Bbase = Bt + (size_t)(n0 + w * 64 + srow) * 4096 + scol;
  u16* lAw = lA + w * 2048;   // 32 rows x 64
  u16* lBw = lB + w * 4096;   // 64 rows x 64

  const int lm = lane & 15;
  const int lk = lane >> 4;            // 0..3
  const int swz = (lane & 7) << 3;     // u16-unit swizzle for frag reads

  for (int kt = 0; kt < 64; ++kt) {
    __syncthreads();
#pragma unroll
    for (int i = 0; i < 4; ++i)
      GLOAD_LDS16(Abase + (size_t)kt * 64 + (size_t)i * 8 * 4096, lAw + i * 512);
#pragma unroll
    for (int i = 0; i < 8; ++i)
      GLOAD_LDS16(Bbase + (size_t)kt * 64 + (size_t)i * 8 * 4096, lBw + i * 512);
    __syncthreads();
#pragma unroll
    for (int ks = 0; ks < 2; ++ks) {
      bf16x8 af[4], bfr[8];
      const int ce = (ks * 32 + lk * 8) ^ swz;
#pragma unroll
      for (int mi = 0; mi < 4; mi++)
        af[mi] = *(const bf16x8*)(lA + (wr * 64 + mi * 16 + lm) * 64 + ce);
#pragma unroll
      for (int ni = 0; ni < 8; ni++)
        bfr[ni] = *(const bf16x8*)(lB + (wc * 128 + ni * 16 + lm) * 64 + ce);
#pragma unroll
      for (int mi = 0; mi < 4; mi++)
#pragma unroll
        for (int ni = 0; ni < 8; ni++)
          acc[mi][ni] = MFMA16(af[mi], bfr[ni], acc[mi][ni]);
    }
  }

#pragma unroll
  for (int mi = 0; mi < 4; mi++) {
#pragma unroll
    for (int ni = 0; ni < 8; ni++) {
      const int mb = m0 + wr * 64 + mi * 16 + lk * 4;  // r=0 row
      const int n = n0 + wc * 128 + ni * 16 + lm;
      if (OUTMODE == 2) {
        // Vt (b,h,hd,s): lane's 4 consecutive s -> one 8B store
        u16x4 vt;
#pragma unroll
        for (int r = 0; r < 4; r++) vt[r] = f2bf(acc[mi][ni][r]);
        u16* o = (u16*)outp;
        *(u16x4*)&o[(size_t)((mb >> 11) * 16 + ((n >> 8) & 15)) * 524288 +
                    (size_t)(n & 255) * 2048 + (mb & 2047)] = vt;
      } else {
        float* o = (float*)outp;
#pragma unroll
        for (int r = 0; r < 4; r++) o[(size_t)(mb + r) * 4096 + n] = acc[mi][ni][r];
      }
    }
  }
}

// ---------------- fused Q+K GEMM with RoPE epilogue (r13-measured) ----------
__global__ __launch_bounds__(256, 2) void k_gemm_qk(const u16* __restrict__ A,
                                                    const u16* __restrict__ Btq,
                                                    const u16* __restrict__ Btk,
                                                    const float* __restrict__ ep,
                                                    const int* __restrict__ pid,
                                                    u16* __restrict__ Qo,
                                                    u16* __restrict__ Ko) {
  __shared__ __attribute__((aligned(16))) u16 lA[128 * 64];
  __shared__ __attribute__((aligned(16))) u16 lBq[128 * 64];
  __shared__ __attribute__((aligned(16))) u16 lBk[128 * 64];
  const int tid = threadIdx.x;
  const int w = tid >> 6, lane = tid & 63;
  const int wr = w >> 1, wc = w & 1;
  const int m0 = blockIdx.y * 128, n0 = blockIdx.x * 128;

  f32x4 accq[4][4], acck[4][4];
#pragma unroll
  for (int i = 0; i < 4; i++)
#pragma unroll
    for (int j = 0; j < 4; j++) {
      accq[i][j] = (f32x4){0.f, 0.f, 0.f, 0.f};
      acck[i][j] = (f32x4){0.f, 0.f, 0.f, 0.f};
    }

  const int srow = lane >> 3;
  const int scol = ((lane & 7) ^ srow) * 8;
  const u16* Abase = A + (size_t)(m0 + w * 32 + srow) * 4096 + scol;
  const u16* Bqb = Btq + (size_t)(n0 + w * 32 + srow) * 4096 + scol;
  const u16* Bkb = Btk + (size_t)(n0 + w * 32 + srow) * 4096 + scol;
  u16* lAw = lA + w * 2048;
  u16* lBqw = lBq + w * 2048;
  u16* lBkw = lBk + w * 2048;

  const int lm = lane & 15;
  const int lk = lane >> 4;
  const int swz = (lane & 7) << 3;

  for (int kt = 0; kt < 64; ++kt) {
    __syncthreads();
#pragma unroll
    for (int i = 0; i < 4; ++i) {
      GLOAD_LDS16(Abase + (size_t)kt * 64 + (size_t)i * 8 * 4096, lAw + i * 512);
      GLOAD_LDS16(Bqb + (size_t)kt * 64 + (size_t)i * 8 * 4096, lBqw + i * 512);
      GLOAD_LDS16(Bkb + (size_t)kt * 64 + (size_t)i * 8 * 4096, lBkw + i * 512);
    }
    __syncthreads();
#pragma unroll
    for (int ks = 0; ks < 2; ++ks) {
      bf16x8 af[4], bfr[4];
      const int ce = (ks * 32 + lk * 8) ^ swz;
#pragma unroll
      for (int mi = 0; mi < 4; mi++)
        af[mi] = *(const bf16x8*)(lA + (wr * 64 + mi * 16 + lm) * 64 + ce);
#pragma unroll
      for (int ni = 0; ni < 4; ni++)
        bfr[ni] = *(const bf16x8*)(lBq + (wc * 64 + ni * 16 + lm) * 64 + ce);
#pragma unroll
      for (int mi = 0; mi < 4; mi++)
#pragma unroll
        for (int ni = 0; ni < 4; ni++)
          accq[mi][ni] = MFMA16(af[mi], bfr[ni], accq[mi][ni]);
#pragma unroll
      for (int ni = 0; ni < 4; ni++)
        bfr[ni] = *(const bf16x8*)(lBk + (wc * 64 + ni * 16 + lm) * 64 + ce);
#pragma unroll
      for (int mi = 0; mi < 4; mi++)
#pragma unroll
        for (int ni = 0; ni < 4; ni++)
          acck[mi][ni] = MFMA16(af[mi], bfr[ni], acck[mi][ni]);
    }
  }

  // RoPE: hd = n & 255 < 64 only when n-block even and wc==0 (wave-uniform)
  const bool ropew = ((blockIdx.x & 1) == 0) && (wc == 0);
  if (ropew) {
#pragma unroll
    for (int mi = 0; mi < 4; mi++) {
#pragma unroll
      for (int r = 0; r < 4; r++) {
        const int m = m0 + wr * 64 + mi * 16 + lk * 4 + r;
        const int pos = pid[(m >> 11) * 2048 + (m & 2047)];
#pragma unroll
        for (int ni = 0; ni < 4; ni++) {
          const int p = (ni * 16 + lm) >> 1;
          const float sn = ep[pos * 64 + p];
          const float cs = ep[pos * 64 + 32 + p];
          float q = accq[mi][ni][r], k = acck[mi][ni][r];
          float qp = __shfl_xor(q, 1, 64), kp = __shfl_xor(k, 1, 64);
          accq[mi][ni][r] = (lm & 1) ? (q * cs + qp * sn) : (q * cs - qp * sn);
          acck[mi][ni][r] = (lm & 1) ? (k * cs + kp * sn) : (k * cs - kp * sn);
        }
      }
    }
  }

#pragma unroll
  for (int mi = 0; mi < 4; mi++) {
#pragma unroll
    for (int ni = 0; ni < 4; ni++) {
#pragma unroll
      for (int r = 0; r < 4; r++) {
        int m = m0 + wr * 64 + mi * 16 + lk * 4 + r;
        int n = n0 + wc * 64 + ni * 16 + lm;
        size_t idx = (size_t)((m >> 11) * 16 + ((n >> 8) & 15)) * 524288 +
                     (size_t)(m & 2047) * 256 + (n & 255);
        Qo[idx] = f2bf(accq[mi][ni][r]);
        Ko[idx] = f2bf(acck[mi][ni][r]);
      }
    }
  }
}

// ---------------- causal flash attention v5 (best measured: 156us) ----------
__global__ __launch_bounds__(512, 2) void k_attn(const u16* __restrict__ Q,
                                                 const u16* __restrict__ K,
                                                 const u16* __restrict__ Vt,
                                                 const float* __restrict__ amask,
                                                 u16* __restrict__ AO) {
  __shared__ __attribute__((aligned(16))) u16 lK[2][64 * 256];   // 2x32KB [kv][hd] swz
  __shared__ __attribute__((aligned(16))) u16 lV[2][256 * 64];   // 2x32KB [d][kv] swz
  __shared__ __attribute__((aligned(16))) u16 lP[8][16 * 64];    // 16KB per-wave P

  const int tid = threadIdx.x, w = tid >> 6, lane = tid & 63;
  const int wg = blockIdx.x;
  const int bh = wg & 31;
  const int qt = (wg < 256) ? (15 - (wg >> 5)) : ((wg - 256) >> 5);
  const int b = bh >> 4;
  const int lm = lane & 15, lk = lane >> 4;
  const size_t head = (size_t)bh * (2048 * 256);
  const int q0 = qt * 128 + w * 16;
  const int swzl = (lane & 7) << 3;

  const int kreg_row = (lane >> 5);
  const int kcol = (lane & 31) * 8;
  const int vreg_row = (lane >> 3);
  const int vcol = (lane & 7) * 8;

#define ASTAGE(t)                                                                \
  {                                                                              \
    const int bb_ = (t) & 1;                                                     \
    const int kv0_ = (t) * 64;                                                   \
    _Pragma("unroll") for (int i_ = 0; i_ < 4; i_++) {                           \
      const int reg_ = w + i_ * 8;                                               \
      const int krow_ = reg_ * 2 + kreg_row;                                     \
      GLOAD_LDS16(K + head + (size_t)(kv0_ + krow_) * 256 +                      \
                      (kcol ^ ((krow_ & 7) << 3)),                               \
                  &lK[bb_][reg_ * 512 + lane * 8]);                              \
      const int vrow_ = reg_ * 8 + vreg_row;                                     \
      GLOAD_LDS16(Vt + head + (size_t)vrow_ * 2048 + kv0_ +                      \
                      (vcol ^ ((vrow_ & 7) << 3)),                               \
                  &lV[bb_][reg_ * 512 + lane * 8]);                              \
    }                                                                            \
  }

  bf16x8 qf[8];
#pragma unroll
  for (int c = 0; c < 8; c++)
    qf[c] = *(const bf16x8*)(Q + head + (size_t)(q0 + lm) * 256 + c * 32 + lk * 8);

  f32x4 o[16];
#pragma unroll
  for (int i = 0; i < 16; i++) o[i] = (f32x4){0.f, 0.f, 0.f, 0.f};
  float m_s = -__builtin_inff();
  float l_s = 0.f;

  const int ntiles = 2 * qt + 2;
  ASTAGE(0);

  for (int t = 0; t < ntiles; ++t) {
    const int kv0 = t * 64;
    const int bb = t & 1;
    float4 amq[4];
#pragma unroll
    for (int kb = 0; kb < 4; kb++)
      amq[kb] = *(const float4*)(amask + b * 2048 + kv0 + kb * 16 + lk * 4);
    if (t + 1 < ntiles) {
      ASTAGE(t + 1);
      asm volatile("s_waitcnt vmcnt(8)" ::: "memory");
    } else {
      asm volatile("s_waitcnt vmcnt(0)" ::: "memory");
    }
    __builtin_amdgcn_s_barrier();

    if (q0 + 15 >= kv0) {
      const u16* lKb = lK[bb];
      const u16* lVb = lV[bb];

      float sx[4][4];
      __builtin_amdgcn_s_setprio(1);
#pragma unroll
      for (int kb = 0; kb < 4; kb++) {
        f32x4 sa = (f32x4){0.f, 0.f, 0.f, 0.f};
        const int kvr = kb * 16 + lm;
#pragma unroll
        for (int c = 0; c < 8; c++) {
          bf16x8 kf = *(const bf16x8*)(lKb + kvr * 256 + ((c * 32 + lk * 8) ^ swzl));
          sa = __builtin_amdgcn_mfma_f32_16x16x32_bf16(kf, qf[c], sa, 0, 0, 0);
        }
#pragma unroll
        for (int r = 0; r < 4; r++)
          sx[kb][r] = sa[r] * 0.0625f + ((const float*)&amq[kb])[r];
      }
      __builtin_amdgcn_s_setprio(0);

      const int q_abs = q0 + lm;
      float tm = -__builtin_inff();
#pragma unroll
      for (int kb = 0; kb < 4; kb++)
#pragma unroll
        for (int r = 0; r < 4; r++) {
          bool valid = (kv0 + kb * 16 + lk * 4 + r) <= q_abs;
          tm = fmaxf(tm, valid ? sx[kb][r] : -__builtin_inff());
        }
      tm = fmaxf(tm, __shfl_xor(tm, 16, 64));
      tm = fmaxf(tm, __shfl_xor(tm, 32, 64));

      if (!__all(tm <= m_s + 8.0f)) {
        float mnew = fmaxf(m_s, tm);
        float alpha = __expf(m_s - mnew);
        m_s = mnew;
        l_s *= alpha;
        float af0 = __shfl(alpha, lk * 4 + 0, 64);
        float af1 = __shfl(alpha, lk * 4 + 1, 64);
        float af2 = __shfl(alpha, lk * 4 + 2, 64);
        float af3 = __shfl(alpha, lk * 4 + 3, 64);
#pragma unroll
        for (int dblk = 0; dblk < 16; dblk++) {
          o[dblk][0] *= af0; o[dblk][1] *= af1;
          o[dblk][2] *= af2; o[dblk][3] *= af3;
        }
      }

      float psum = 0.f;
#pragma unroll
      for (int kb = 0; kb < 4; kb++) {
        u16x4 ph;
#pragma unroll
        for (int r = 0; r < 4; r++) {
          bool valid = (kv0 + kb * 16 + lk * 4 + r) <= q_abs;
          float p = valid ? __expf(sx[kb][r] - m_s) : 0.f;
          psum += p;
          ph[r] = f2bf(p);
        }
        *(u16x4*)(&lP[w][lm * 64 + ((kb * 16 + lk * 4) ^ swzl)]) = ph;
      }
      psum += __shfl_xor(psum, 16, 64);
      psum += __shfl_xor(psum, 32, 64);
      l_s += psum;

      bf16x8 pa[2];
#pragma unroll
      for (int kh = 0; kh < 2; kh++)
        pa[kh] = *(const bf16x8*)(&lP[w][lm * 64 + ((lk * 8 + kh * 32) ^ swzl)]);
      __builtin_amdgcn_s_setprio(1);
#pragma unroll
      for (int dblk = 0; dblk < 16; dblk++) {
        const int dr = dblk * 16 + lm;
#pragma unroll
        for (int kh = 0; kh < 2; kh++) {
          bf16x8 vf = *(const bf16x8*)(lVb + dr * 64 + ((lk * 8 + kh * 32) ^ swzl));
          o[dblk] = __builtin_amdgcn_mfma_f32_16x16x32_bf16(pa[kh], vf, o[dblk], 0, 0, 0);
        }
      }
      __builtin_amdgcn_s_setprio(0);
    }
    __builtin_amdgcn_s_barrier();
  }
#undef ASTAGE

  float linv[4];
#pragma unroll
  for (int r = 0; r < 4; r++) linv[r] = 1.0f / __shfl(l_s, lk * 4 + r, 64);
#pragma unroll
  for (int r = 0; r < 4; r++) {
    const int s_abs = q0 + lk * 4 + r;
#pragma unroll
    for (int dblk = 0; dblk < 16; dblk++) {
      int d = (bh & 15) * 256 + dblk * 16 + lm;
      AO[((size_t)b * 2048 + s_abs) * 4096 + d] = f2bf(o[dblk][r] * linv[r]);
    }
  }
}

extern "C" void kernel_launch(void* const* d_in, const int* in_sizes, int n_in,
                              void* d_out, int out_size, void* d_ws, size_t ws_size,
                              hipStream_t stream) {
  (void)in_sizes; (void)n_in; (void)out_size; (void)ws_size;
  const float* hs = (const float*)d_in[0];
  const float* Wq = (const float*)d_in[1];
  const float* Wk = (const float*)d_in[2];
  const float* Wv = (const float*)d_in[3];
  const float* Wo = (const float*)d_in[4];
  const float* ep = (const float*)d_in[5];
  const float* am = (const float*)d_in[6];
  const int* pid = (const int*)d_in[7];

  u16* r0 = (u16*)d_ws;        // hidden bf16, later AO
  u16* r1 = r0 + R_ELEMS;      // Wt_q -> Wt_v -> Wt_o
  u16* r2 = r1 + R_ELEMS;      // Wt_k -> Vt
  u16* r3 = r2 + R_ELEMS;      // Q (b,h,s,hd), rope'd
  u16* r4 = r3 + R_ELEMS;      // K (b,h,s,hd), rope'd
  float* out = (float*)d_out;

  dim3 b256(256), b512(512), bT(64, 4);
  k_cvt<<<dim3(8192), b256, 0, stream>>>(hs, r0, 16777216 / 8);

  k_transpose_w<<<dim3(64, 64), bT, 0, stream>>>(Wq, r1);
  k_transpose_w<<<dim3(64, 64), bT, 0, stream>>>(Wk, r2);
  k_gemm_qk<<<dim3(32, 32), b256, 0, stream>>>(r0, r1, r2, ep, pid, r3, r4);

  k_transpose_w<<<dim3(64, 64), bT, 0, stream>>>(Wv, r1);
  k_gemm<2><<<dim3(16, 32), b256, 0, stream>>>(r0, r1, r2);   // Vt -> r2

  k_attn<<<dim3(512), b512, 0, stream>>>(r3, r4, r2, am, r0); // AO -> r0

  k_transpose_w<<<dim3(64, 64), bT, 0, stream>>>(Wo, r1);
  k_gemm<1><<<dim3(16, 32), b256, 0, stream>>>(r0, r1, out);
}